// Round 3
// baseline (302.784 us; speedup 1.0000x reference)
//
#include <hip/hip_runtime.h>

// B=512, P=64, K=8, D=512, T=50000
// out: [B*P, 2*D] fp32
#define BB 512
#define PP 64
#define KK 8
#define DD 512

typedef float v4f __attribute__((ext_vector_type(4)));

// Two-pass split so each pass's read working set fits the 256 MB Infinity
// Cache with slack (single-pass read set ~163 MB unique but ~600 MB logical
// traffic -> reuse distances ~300 MB -> L3 thrash, measured 290 MB fetch vs
// 163 compulsory).
//  Pass 1: read set = inputs (64 MB) + idx. Computes sim weights -> d_ws,
//          copies focal half of out.
//  Pass 2: read set = title rows (~95 MB unique) + sim + ntk. Weighted title
//          sum -> graph half of out.

// ---------------- Pass 1: logits -> softmax -> sim; focal copy --------------
__global__ __launch_bounds__(256) void han_pass1(
    const float* __restrict__ inputs,       // [B,P,D]
    const int*   __restrict__ nbr_batch,    // [B,P,K]
    const int*   __restrict__ nbr_job,      // [B,P,K]
    const int*   __restrict__ nbr_mask,     // [B,P,K]
    float*       __restrict__ out,          // [B*P, 2*D]
    float*       __restrict__ sim_ws)       // [B*P, K]
{
    const int lane = threadIdx.x & 63;
    const int wave = threadIdx.x >> 6;
    const int row  = blockIdx.x * 4 + wave;

    // focal embedding (coalesced; also streams `inputs` through L3 so the
    // random gathers below mostly hit)
    const float4* inp4 = (const float4*)(inputs + (size_t)row * DD);
    const float4 fa = inp4[lane];        // d = lane*4
    const float4 fb = inp4[lane + 64];   // d = 256 + lane*4

    const int4* nb4 = (const int4*)(nbr_batch + row * KK);
    const int4* nj4 = (const int4*)(nbr_job   + row * KK);
    const int4* nm4 = (const int4*)(nbr_mask  + row * KK);
    int nbk[KK], njk[KK], nmk[KK];
    *(int4*)&nbk[0] = nb4[0]; *(int4*)&nbk[4] = nb4[1];
    *(int4*)&njk[0] = nj4[0]; *(int4*)&njk[4] = nj4[1];
    *(int4*)&nmk[0] = nm4[0]; *(int4*)&nmk[4] = nm4[1];

    // ---- hoisted gather loads: all 16 float4 loads issue before any use ----
    float4 ga[KK], gb[KK];
    #pragma unroll
    for (int k = 0; k < KK; ++k) {
        if (nmk[k]) {   // wave-uniform branch
            const float4* g4 = (const float4*)(inputs +
                ((size_t)nbk[k] * PP + (size_t)njk[k]) * DD);
            ga[k] = g4[lane];
            gb[k] = g4[lane + 64];
        } else {
            ga[k] = make_float4(0.f,0.f,0.f,0.f);
            gb[k] = make_float4(0.f,0.f,0.f,0.f);
        }
    }

    // ---- dots ----
    float d[KK];
    #pragma unroll
    for (int k = 0; k < KK; ++k) {
        d[k] = fa.x*ga[k].x + fa.y*ga[k].y + fa.z*ga[k].z + fa.w*ga[k].w
             + fb.x*gb[k].x + fb.y*gb[k].y + fb.z*gb[k].z + fb.w*gb[k].w;
    }

    // ---- 8 independent butterfly reductions, interleaved (pipelined) ----
    #pragma unroll
    for (int off = 32; off >= 1; off >>= 1) {
        #pragma unroll
        for (int k = 0; k < KK; ++k)
            d[k] += __shfl_xor(d[k], off, 64);
    }

    // ---- masked softmax (replicated per lane) ----
    float logit[KK];
    #pragma unroll
    for (int k = 0; k < KK; ++k) logit[k] = nmk[k] ? d[k] : -1e9f;
    float m = logit[0];
    #pragma unroll
    for (int k = 1; k < KK; ++k) m = fmaxf(m, logit[k]);
    float e[KK]; float s = 0.0f;
    #pragma unroll
    for (int k = 0; k < KK; ++k) { e[k] = expf(logit[k] - m); s += e[k]; }
    const float inv = 1.0f / s;

    float sim[KK];
    #pragma unroll
    for (int k = 0; k < KK; ++k) sim[k] = nmk[k] ? e[k] * inv : 0.0f;

    // lanes 0,1 write the 8 sim weights (values replicated across the wave)
    if (lane < 2) {
        float4 sv = lane == 0 ? make_float4(sim[0],sim[1],sim[2],sim[3])
                              : make_float4(sim[4],sim[5],sim[6],sim[7]);
        ((float4*)(sim_ws + (size_t)row * KK))[lane] = sv;
    }

    // focal half of out
    v4f* o4 = (v4f*)(out + (size_t)row * (2 * DD));
    v4f va = {fa.x, fa.y, fa.z, fa.w};
    v4f vb = {fb.x, fb.y, fb.z, fb.w};
    __builtin_nontemporal_store(va, o4 + lane);
    __builtin_nontemporal_store(vb, o4 + lane + 64);
}

// ---------------- Pass 2: weighted title sum -> graph half ------------------
__global__ __launch_bounds__(256) void han_pass2(
    const float* __restrict__ title,        // [T,D]
    const int*   __restrict__ nbr_title,    // [B,P,K]
    const float* __restrict__ sim_ws,       // [B*P, K]
    float*       __restrict__ out)          // [B*P, 2*D]
{
    const int lane = threadIdx.x & 63;
    const int wave = threadIdx.x >> 6;
    const int row  = blockIdx.x * 4 + wave;

    const int4* nt4 = (const int4*)(nbr_title + row * KK);
    int ntk[KK];
    *(int4*)&ntk[0] = nt4[0]; *(int4*)&ntk[4] = nt4[1];

    const float4* s4 = (const float4*)(sim_ws + (size_t)row * KK);
    float sim[KK];
    *(float4*)&sim[0] = s4[0]; *(float4*)&sim[4] = s4[1];

    // hoisted gathers: issue all title loads before any FMA
    // (sim[k]==0 exactly for masked slots; skipping them is exact)
    float4 ta[KK], tb[KK];
    #pragma unroll
    for (int k = 0; k < KK; ++k) {
        if (sim[k] != 0.0f) {   // wave-uniform
            const float4* t4 = (const float4*)(title + (size_t)ntk[k] * DD);
            ta[k] = t4[lane];
            tb[k] = t4[lane + 64];
        }
    }

    float4 oa = make_float4(0.f,0.f,0.f,0.f);
    float4 ob = make_float4(0.f,0.f,0.f,0.f);
    #pragma unroll
    for (int k = 0; k < KK; ++k) {
        if (sim[k] != 0.0f) {
            const float w = sim[k];
            oa.x += w * ta[k].x; oa.y += w * ta[k].y;
            oa.z += w * ta[k].z; oa.w += w * ta[k].w;
            ob.x += w * tb[k].x; ob.y += w * tb[k].y;
            ob.z += w * tb[k].z; ob.w += w * tb[k].w;
        }
    }

    v4f* o4 = (v4f*)(out + (size_t)row * (2 * DD));
    v4f vc = {oa.x, oa.y, oa.z, oa.w};
    v4f vd = {ob.x, ob.y, ob.z, ob.w};
    __builtin_nontemporal_store(vc, o4 + lane + 128);
    __builtin_nontemporal_store(vd, o4 + lane + 192);
}

extern "C" void kernel_launch(void* const* d_in, const int* in_sizes, int n_in,
                              void* d_out, int out_size, void* d_ws, size_t ws_size,
                              hipStream_t stream) {
    const float* inputs    = (const float*)d_in[0];
    const float* title     = (const float*)d_in[1];
    const int*   nbr_batch = (const int*)d_in[2];
    const int*   nbr_job   = (const int*)d_in[3];
    const int*   nbr_title = (const int*)d_in[4];
    const int*   nbr_mask  = (const int*)d_in[5];
    float*       out       = (float*)d_out;
    float*       sim_ws    = (float*)d_ws;   // 32768*8*4 = 1 MB

    const int rows = BB * PP;
    dim3 grid(rows / 4);   // 4 waves (rows) per 256-thread block
    dim3 block(256);
    han_pass1<<<grid, block, 0, stream>>>(
        inputs, nbr_batch, nbr_job, nbr_mask, out, sim_ws);
    han_pass2<<<grid, block, 0, stream>>>(
        title, nbr_title, sim_ws, out);
}